// Round 6
// baseline (337.734 us; speedup 1.0000x reference)
//
#include <hip/hip_runtime.h>

// FeatLUT: out[f] = quantize( mean_p( msb[idx_m(p)][f] + lsb[idx_l(p)][f] ) )
// idx = 16*(289*c0 + 17*c1 + c2) -> only 17^3 = 4913 distinct rows used.
// R1: same-cacheline global atomics serialize (417us) -> per-block partials.
// R2: 1024x256 stream+LDS-hist+per-block dot = 54us (VALU 32%, dot ~2/3).
// R3/R4: register cliffs (VGPR 32 / 64 caps -> spills -> 150-166us).
// R5: two-stage (hist -> ghist -> reduce) = hist 34us + reduce 43us; reduce
//     had 308 blocks (8.9% occ, latency-bound), hist capped at 16 waves/CU.
// R6: u16-packed LDS hist (19.7KB -> 8 blocks/CU) with SB=2048 grid (32
//     waves/CU), reduce widened to 64-row groups (2464 blocks). ws-tiered.

#define NBINS 4913            // 17^3
#define NPIX  (2048 * 2048)
#define G4    (NPIX / 4)      // 1048576 float4 groups per channel plane
#define NFEAT 20
#define WPH   2457            // u32 words per table histogram (u16 pairs)
#define HROW  (2 * WPH)       // 4914 valid words per block row (msb | lsb)
#define ROWW  4928            // padded row stride in words (multiple of 64)
#define STRIPS 77             // ceil(HROW/64)

// ---------------------------------------------------------------------------
// Kernel 0: compact used LUT rows (row 16*j) into dense 20B rows (5 dwords),
// row-major (cm[j*5+k]). Handles both harness table layouts (raw int8 bytes,
// or int8 widened to int32 — random packed bytes never look like 16
// consecutive ints in [-32,32)). Also zeroes the completion counter.
// ---------------------------------------------------------------------------
__global__ __launch_bounds__(256) void compact_k(const int* __restrict__ msb,
                                                 const int* __restrict__ lsb,
                                                 int* __restrict__ cm,
                                                 int* __restrict__ cl,
                                                 unsigned* __restrict__ done) {
    if (blockIdx.x == 0 && threadIdx.x == 0) *done = 0u;

    int ok = 1;
#pragma unroll
    for (int i = 0; i < 16; ++i) {
        int v = msb[i];
        ok &= (v >= -32 && v < 32);
    }
    const bool is_int32 = (ok != 0);

    const int total = NBINS * 5;
    const int stride = gridDim.x * 256;
    for (int t = blockIdx.x * 256 + threadIdx.x; t < total; t += stride) {
        int j = t / 5;
        int k = t - j * 5;
        int wm, wl;
        if (is_int32) {
            const int* rm = msb + j * 320 + k * 4;  // row 16j -> elem 320j
            const int* rl = lsb + j * 320 + k * 4;
            wm = (int)((unsigned)(rm[0] & 0xff) | ((unsigned)(rm[1] & 0xff) << 8) |
                       ((unsigned)(rm[2] & 0xff) << 16) | ((unsigned)(rm[3] & 0xff) << 24));
            wl = (int)((unsigned)(rl[0] & 0xff) | ((unsigned)(rl[1] & 0xff) << 8) |
                       ((unsigned)(rl[2] & 0xff) << 16) | ((unsigned)(rl[3] & 0xff) << 24));
        } else {
            wm = msb[j * 80 + k];  // row 16j at byte 320j -> dword 80j
            wl = lsb[j * 80 + k];
        }
        cm[t] = wm;
        cl[t] = wl;
    }
}

// ---------------------------------------------------------------------------
// Stage 1: stream + u16-packed LDS histogram (19.7 KB -> 8 blocks/CU), then
// copy the packed row to global. Per-block per-table count <= NPIX/(SB*..)
// <= 4096 -> u16 provably safe. No dot -> low register pressure.
// ---------------------------------------------------------------------------
template <int SB_>
__global__ __launch_bounds__(256) void hist_k(const float* __restrict__ xin,
                                              const float* __restrict__ xs,
                                              unsigned* __restrict__ ghist) {
    __shared__ unsigned h32[HROW];  // u16 pairs: msb words [0,WPH), lsb [WPH,HROW)
    for (int i = threadIdx.x; i < HROW; i += 256) h32[i] = 0u;
    __syncthreads();

    const float4* a = (const float4*)xin;
    const float4* b = (const float4*)xs;
    for (int g = blockIdx.x * 256 + threadIdx.x; g < G4; g += SB_ * 256) {
        float4 a0 = a[g], a1 = a[g + G4], a2 = a[g + 2 * G4];
        float4 b0 = b[g], b1 = b[g + G4], b2 = b[g + 2 * G4];

        int m0 = (int)fmaf(a0.x, 289.0f, fmaf(a1.x, 17.0f, a2.x));
        int m1 = (int)fmaf(a0.y, 289.0f, fmaf(a1.y, 17.0f, a2.y));
        int m2 = (int)fmaf(a0.z, 289.0f, fmaf(a1.z, 17.0f, a2.z));
        int m3 = (int)fmaf(a0.w, 289.0f, fmaf(a1.w, 17.0f, a2.w));
        int s0 = (int)fmaf(b0.x, 289.0f, fmaf(b1.x, 17.0f, b2.x));
        int s1 = (int)fmaf(b0.y, 289.0f, fmaf(b1.y, 17.0f, b2.y));
        int s2 = (int)fmaf(b0.z, 289.0f, fmaf(b1.z, 17.0f, b2.z));
        int s3 = (int)fmaf(b0.w, 289.0f, fmaf(b1.w, 17.0f, b2.w));

        atomicAdd(&h32[m0 >> 1], 1u << ((m0 & 1) << 4));
        atomicAdd(&h32[m1 >> 1], 1u << ((m1 & 1) << 4));
        atomicAdd(&h32[m2 >> 1], 1u << ((m2 & 1) << 4));
        atomicAdd(&h32[m3 >> 1], 1u << ((m3 & 1) << 4));
        atomicAdd(&h32[WPH + (s0 >> 1)], 1u << ((s0 & 1) << 4));
        atomicAdd(&h32[WPH + (s1 >> 1)], 1u << ((s1 & 1) << 4));
        atomicAdd(&h32[WPH + (s2 >> 1)], 1u << ((s2 & 1) << 4));
        atomicAdd(&h32[WPH + (s3 >> 1)], 1u << ((s3 & 1) << 4));
    }
    __syncthreads();

    unsigned* row = ghist + (size_t)blockIdx.x * ROWW;
    for (int w = threadIdx.x; w < HROW; w += 256) row[w] = h32[w];
}

// ---------------------------------------------------------------------------
// Stage 2: block (strip, grp) sums a 64-word column strip over 64 rows
// (coalesced 256B wave reads, 16 loads/thread), dots the strip's 128 bins
// against the compact table, block-reduces -> per-block partial; last block
// of STRIPS*RGRP_ finalizes.  ROWS = 64*RGRP_.
// ---------------------------------------------------------------------------
template <int RGRP_>
__global__ __launch_bounds__(256) void reduce_k(const unsigned* __restrict__ ghist,
                                                const int* __restrict__ cm,
                                                const int* __restrict__ cl,
                                                int* __restrict__ partial,
                                                unsigned* __restrict__ done,
                                                float* __restrict__ out) {
    const int NG = STRIPS * RGRP_;
    __shared__ int scnt[128];
    __shared__ int wsum[4][NFEAT];
    __shared__ unsigned is_last;

    const int strip = blockIdx.x % STRIPS;
    const int grp = blockIdx.x / STRIPS;
    const int w0 = strip * 64;
    const int wlane = threadIdx.x & 63;
    const int wv = threadIdx.x >> 6;

    if (threadIdx.x < 128) scnt[threadIdx.x] = 0;
    __syncthreads();

    // column sums over this 64-row group (lanes read 64 consecutive words)
    unsigned slo = 0, shi = 0;
    const int w = w0 + wlane;
    if (w < HROW) {
        const size_t base = (size_t)(grp * 64 + wv) * ROWW + w;
#pragma unroll
        for (int k = 0; k < 16; ++k) {
            unsigned v = ghist[base + (size_t)(4 * k) * ROWW];
            slo += v & 0xFFFFu;
            shi += v >> 16;
        }
    }
    atomicAdd(&scnt[2 * wlane], (int)slo);
    atomicAdd(&scnt[2 * wlane + 1], (int)shi);
    __syncthreads();

    // dot the strip's 128 bins against table rows
    int acc[NFEAT];
#pragma unroll
    for (int f = 0; f < NFEAT; ++f) acc[f] = 0;

    if (threadIdx.x < 128) {
        int s = threadIdx.x;
        int word = w0 + (s >> 1);
        if (word < HROW) {
            int tb = (word >= WPH);
            int wi = word - tb * WPH;
            int j = 2 * wi + (s & 1);
            if (j < NBINS) {
                int c = scnt[s];
                if (c) {
                    const int* r = (tb ? cl : cm) + j * 5;
#pragma unroll
                    for (int k = 0; k < 5; ++k) {
                        int t = r[k];
                        acc[4 * k + 0] += c * ((t << 24) >> 24);
                        acc[4 * k + 1] += c * ((t << 16) >> 24);
                        acc[4 * k + 2] += c * ((t << 8) >> 24);
                        acc[4 * k + 3] += c * (t >> 24);
                    }
                }
            }
        }
    }

    // block reduce: wave butterfly -> LDS rows -> per-block partial
    const int lane = threadIdx.x & 63;
#pragma unroll
    for (int f = 0; f < NFEAT; ++f) {
        int v = acc[f];
#pragma unroll
        for (int o = 32; o > 0; o >>= 1) v += __shfl_xor(v, o, 64);
        if (lane == 0) wsum[wv][f] = v;
    }
    __syncthreads();
    if (threadIdx.x < NFEAT) {
        int f = threadIdx.x;
        partial[blockIdx.x * NFEAT + f] = wsum[0][f] + wsum[1][f] + wsum[2][f] + wsum[3][f];
    }
    __threadfence();
    __syncthreads();
    if (threadIdx.x == 0) is_last = (atomicAdd(done, 1u) == (unsigned)(NG - 1));
    __syncthreads();

    if (is_last) {
        __threadfence();  // acquire
        if (threadIdx.x < NFEAT) scnt[threadIdx.x] = 0;
        __syncthreads();
        for (int i = threadIdx.x; i < NG * NFEAT; i += 256)
            atomicAdd(&scnt[i % NFEAT], partial[i]);
        __syncthreads();
        if (threadIdx.x < NFEAT) {
            // mean*4 = S / 2^20 exact in double; RNE rint == jnp.round
            double m4 = (double)scnt[threadIdx.x] * (1.0 / 1048576.0);
            float v = (float)(rint(m4) * 0.25);
            v = fminf(fmaxf(v, -32.0f), 31.75f);
            out[threadIdx.x] = v;
        }
    }
}

// ---------------------------------------------------------------------------
// Fallback (R2 verbatim, proven 54us) if ws can't hold the histograms.
// ---------------------------------------------------------------------------
__global__ __launch_bounds__(256) void feat_fallback(const float* __restrict__ xin,
                                                     const float* __restrict__ xs,
                                                     const int* __restrict__ cm,
                                                     const int* __restrict__ cl,
                                                     int* __restrict__ partial,
                                                     unsigned* __restrict__ done,
                                                     float* __restrict__ out) {
    __shared__ int hist[2 * NBINS];
    __shared__ int wsum[4][NFEAT];
    __shared__ unsigned is_last;
    for (int i = threadIdx.x; i < 2 * NBINS; i += 256) hist[i] = 0;
    __syncthreads();

    const float4* a = (const float4*)xin;
    const float4* b = (const float4*)xs;
    for (int g = blockIdx.x * 256 + threadIdx.x; g < G4; g += 1024 * 256) {
        float4 a0 = a[g], a1 = a[g + G4], a2 = a[g + 2 * G4];
        float4 b0 = b[g], b1 = b[g + G4], b2 = b[g + 2 * G4];
        int m0 = (int)fmaf(a0.x, 289.0f, fmaf(a1.x, 17.0f, a2.x));
        int m1 = (int)fmaf(a0.y, 289.0f, fmaf(a1.y, 17.0f, a2.y));
        int m2 = (int)fmaf(a0.z, 289.0f, fmaf(a1.z, 17.0f, a2.z));
        int m3 = (int)fmaf(a0.w, 289.0f, fmaf(a1.w, 17.0f, a2.w));
        int s0 = (int)fmaf(b0.x, 289.0f, fmaf(b1.x, 17.0f, b2.x));
        int s1 = (int)fmaf(b0.y, 289.0f, fmaf(b1.y, 17.0f, b2.y));
        int s2 = (int)fmaf(b0.z, 289.0f, fmaf(b1.z, 17.0f, b2.z));
        int s3 = (int)fmaf(b0.w, 289.0f, fmaf(b1.w, 17.0f, b2.w));
        atomicAdd(&hist[m0], 1);
        atomicAdd(&hist[m1], 1);
        atomicAdd(&hist[m2], 1);
        atomicAdd(&hist[m3], 1);
        atomicAdd(&hist[NBINS + s0], 1);
        atomicAdd(&hist[NBINS + s1], 1);
        atomicAdd(&hist[NBINS + s2], 1);
        atomicAdd(&hist[NBINS + s3], 1);
    }
    __syncthreads();

    int acc[NFEAT];
#pragma unroll
    for (int f = 0; f < NFEAT; ++f) acc[f] = 0;
    for (int j = threadIdx.x; j < NBINS; j += 256) {
        int hm = hist[j];
        int hl = hist[NBINS + j];
        const int* rm = cm + j * 5;
        const int* rl = cl + j * 5;
#pragma unroll
        for (int k = 0; k < 5; ++k) {
            int wm = rm[k];
            int wl = rl[k];
            acc[4 * k + 0] += hm * ((wm << 24) >> 24) + hl * ((wl << 24) >> 24);
            acc[4 * k + 1] += hm * ((wm << 16) >> 24) + hl * ((wl << 16) >> 24);
            acc[4 * k + 2] += hm * ((wm << 8) >> 24) + hl * ((wl << 8) >> 24);
            acc[4 * k + 3] += hm * (wm >> 24) + hl * (wl >> 24);
        }
    }

    const int lane = threadIdx.x & 63;
    const int wv = threadIdx.x >> 6;
#pragma unroll
    for (int f = 0; f < NFEAT; ++f) {
        int v = acc[f];
#pragma unroll
        for (int o = 32; o > 0; o >>= 1) v += __shfl_xor(v, o, 64);
        if (lane == 0) wsum[wv][f] = v;
    }
    __syncthreads();
    if (threadIdx.x < NFEAT) {
        int f = threadIdx.x;
        partial[blockIdx.x * NFEAT + f] = wsum[0][f] + wsum[1][f] + wsum[2][f] + wsum[3][f];
    }
    __threadfence();
    __syncthreads();
    if (threadIdx.x == 0) is_last = (atomicAdd(done, 1u) == 1023u);
    __syncthreads();
    if (is_last) {
        __threadfence();
        if (threadIdx.x < NFEAT) hist[threadIdx.x] = 0;
        __syncthreads();
        for (int i = threadIdx.x; i < 1024 * NFEAT; i += 256)
            atomicAdd(&hist[i % NFEAT], partial[i]);
        __syncthreads();
        if (threadIdx.x < NFEAT) {
            double m4 = (double)hist[threadIdx.x] * (1.0 / 1048576.0);
            float v = (float)(rint(m4) * 0.25);
            v = fminf(fmaxf(v, -32.0f), 31.75f);
            out[threadIdx.x] = v;
        }
    }
}

extern "C" void kernel_launch(void* const* d_in, const int* in_sizes, int n_in,
                              void* d_out, int out_size, void* d_ws, size_t ws_size,
                              hipStream_t stream) {
    const float* xin = (const float*)d_in[0];
    const float* xs = (const float*)d_in[1];
    const int* msb = (const int*)d_in[2];
    const int* lsb = (const int*)d_in[3];
    float* out = (float*)d_out;

    // ws: cm 96KiB | cl 96KiB | partial 2464*20*4=192.6KiB | done | ghist
    char* base = (char*)d_ws;
    int* cm = (int*)base;
    int* cl = (int*)(base + 98304);
    int* partial = (int*)(base + 196608);
    unsigned* done = (unsigned*)(base + 196608 + 197376);
    unsigned* ghist = (unsigned*)(base + 196608 + 197632);  // 64B-aligned
    const size_t hdr = 196608 + 197632;
    const size_t need2048 = hdr + (size_t)2048 * ROWW * 4;  // ~40.7 MB
    const size_t need1024 = hdr + (size_t)1024 * ROWW * 4;  // ~20.6 MB

    compact_k<<<96, 256, 0, stream>>>(msb, lsb, cm, cl, done);
    if (ws_size >= need2048) {
        hist_k<2048><<<2048, 256, 0, stream>>>(xin, xs, ghist);
        reduce_k<32><<<STRIPS * 32, 256, 0, stream>>>(ghist, cm, cl, partial, done, out);
    } else if (ws_size >= need1024) {
        hist_k<1024><<<1024, 256, 0, stream>>>(xin, xs, ghist);
        reduce_k<16><<<STRIPS * 16, 256, 0, stream>>>(ghist, cm, cl, partial, done, out);
    } else {
        feat_fallback<<<1024, 256, 0, stream>>>(xin, xs, cm, cl, partial, done, out);
    }
}

// Round 7
// 179.925 us; speedup vs baseline: 1.8771x; 1.8771x over previous
//
#include <hip/hip_runtime.h>

// FeatLUT: out[f] = quantize( mean_p( msb[idx_m(p)][f] + lsb[idx_l(p)][f] ) )
// idx = 16*(289*c0 + 17*c1 + c2) -> only 17^3 = 4913 distinct rows used.
// R1: same-cacheline global atomics serialize (417us) -> per-block partials.
// R2: stream+LDS-hist+per-block dot = 54us. R3/R4: VGPR cliffs (spills).
// R5/R6: two-stage with COLUMN-strided stage-2 reads: HBM row-buffer thrash,
//        dur == FETCH/rate at 246 / 102 GB/s (worse with MORE blocks).
// R7: stage 2 reads ghist CONTIGUOUSLY: 256 blocks x 8 whole rows (157.7KB
//     sequential, uint4), packed-u16 register column sums (8x2048<65536,
//     carry-free), LDS dump, R2-style dot, last-block finalize.

#define NBINS 4913            // 17^3
#define NPIX  (2048 * 2048)
#define G4    (NPIX / 4)      // 1048576 float4 groups per channel plane
#define NFEAT 20
#define WPH   2457            // u32 words per table histogram (u16 pairs)
#define HROW  (2 * WPH)       // 4914 valid words per block row (msb | lsb)
#define ROWW  4928            // padded row stride in words (16B-multiple)
#define R4W   (ROWW / 4)      // 1232 uint4 per row
#define STRIPS 77
#define FB    256             // stage-2 blocks

// ---------------------------------------------------------------------------
// Kernel 0: compact used LUT rows (row 16*j) into dense 20B rows (5 dwords),
// row-major. Handles both harness table layouts (raw int8 bytes, or int8
// widened to int32). Also zeroes the completion counter.
// ---------------------------------------------------------------------------
__global__ __launch_bounds__(256) void compact_k(const int* __restrict__ msb,
                                                 const int* __restrict__ lsb,
                                                 int* __restrict__ cm,
                                                 int* __restrict__ cl,
                                                 unsigned* __restrict__ done) {
    if (blockIdx.x == 0 && threadIdx.x == 0) *done = 0u;

    int ok = 1;
#pragma unroll
    for (int i = 0; i < 16; ++i) {
        int v = msb[i];
        ok &= (v >= -32 && v < 32);
    }
    const bool is_int32 = (ok != 0);

    const int total = NBINS * 5;
    const int stride = gridDim.x * 256;
    for (int t = blockIdx.x * 256 + threadIdx.x; t < total; t += stride) {
        int j = t / 5;
        int k = t - j * 5;
        int wm, wl;
        if (is_int32) {
            const int* rm = msb + j * 320 + k * 4;  // row 16j -> elem 320j
            const int* rl = lsb + j * 320 + k * 4;
            wm = (int)((unsigned)(rm[0] & 0xff) | ((unsigned)(rm[1] & 0xff) << 8) |
                       ((unsigned)(rm[2] & 0xff) << 16) | ((unsigned)(rm[3] & 0xff) << 24));
            wl = (int)((unsigned)(rl[0] & 0xff) | ((unsigned)(rl[1] & 0xff) << 8) |
                       ((unsigned)(rl[2] & 0xff) << 16) | ((unsigned)(rl[3] & 0xff) << 24));
        } else {
            wm = msb[j * 80 + k];  // row 16j at byte 320j -> dword 80j
            wl = lsb[j * 80 + k];
        }
        cm[t] = wm;
        cl[t] = wl;
    }
}

// ---------------------------------------------------------------------------
// Stage 1: stream + u16-packed LDS histogram (19.7KB -> 8 blocks/CU, 32
// waves/CU), write the packed row zero-padded to ROWW (stage 2 sweeps pads).
// Per-block per-table count <= NPIX/SB_ <= 4096 -> u16 provably safe.
// ---------------------------------------------------------------------------
template <int SB_>
__global__ __launch_bounds__(256) void hist_k(const float* __restrict__ xin,
                                              const float* __restrict__ xs,
                                              unsigned* __restrict__ ghist) {
    __shared__ unsigned h32[HROW];  // u16 pairs: msb [0,WPH), lsb [WPH,HROW)
    for (int i = threadIdx.x; i < HROW; i += 256) h32[i] = 0u;
    __syncthreads();

    const float4* a = (const float4*)xin;
    const float4* b = (const float4*)xs;
    for (int g = blockIdx.x * 256 + threadIdx.x; g < G4; g += SB_ * 256) {
        float4 a0 = a[g], a1 = a[g + G4], a2 = a[g + 2 * G4];
        float4 b0 = b[g], b1 = b[g + G4], b2 = b[g + 2 * G4];

        int m0 = (int)fmaf(a0.x, 289.0f, fmaf(a1.x, 17.0f, a2.x));
        int m1 = (int)fmaf(a0.y, 289.0f, fmaf(a1.y, 17.0f, a2.y));
        int m2 = (int)fmaf(a0.z, 289.0f, fmaf(a1.z, 17.0f, a2.z));
        int m3 = (int)fmaf(a0.w, 289.0f, fmaf(a1.w, 17.0f, a2.w));
        int s0 = (int)fmaf(b0.x, 289.0f, fmaf(b1.x, 17.0f, b2.x));
        int s1 = (int)fmaf(b0.y, 289.0f, fmaf(b1.y, 17.0f, b2.y));
        int s2 = (int)fmaf(b0.z, 289.0f, fmaf(b1.z, 17.0f, b2.z));
        int s3 = (int)fmaf(b0.w, 289.0f, fmaf(b1.w, 17.0f, b2.w));

        atomicAdd(&h32[m0 >> 1], 1u << ((m0 & 1) << 4));
        atomicAdd(&h32[m1 >> 1], 1u << ((m1 & 1) << 4));
        atomicAdd(&h32[m2 >> 1], 1u << ((m2 & 1) << 4));
        atomicAdd(&h32[m3 >> 1], 1u << ((m3 & 1) << 4));
        atomicAdd(&h32[WPH + (s0 >> 1)], 1u << ((s0 & 1) << 4));
        atomicAdd(&h32[WPH + (s1 >> 1)], 1u << ((s1 & 1) << 4));
        atomicAdd(&h32[WPH + (s2 >> 1)], 1u << ((s2 & 1) << 4));
        atomicAdd(&h32[WPH + (s3 >> 1)], 1u << ((s3 & 1) << 4));
    }
    __syncthreads();

    unsigned* row = ghist + (size_t)blockIdx.x * ROWW;
    for (int w = threadIdx.x; w < ROWW; w += 256)
        row[w] = (w < HROW) ? h32[w] : 0u;
}

// ---------------------------------------------------------------------------
// Stage 2: FB blocks; block g streams rows [g*RPB_, (g+1)*RPB_) of ghist
// CONTIGUOUSLY (uint4 = 1KB/wave-request), packed-u16 column sums in 5 uint4
// registers (carry-free: RPB_ * max_count <= 16384 < 65536), dump to LDS,
// dot vs compact tables, block reduce -> partial; last block finalizes.
// ---------------------------------------------------------------------------
template <int RPB_>
__global__ __launch_bounds__(256) void colsum_k(const unsigned* __restrict__ ghist,
                                                const int* __restrict__ cm,
                                                const int* __restrict__ cl,
                                                int* __restrict__ partial,
                                                unsigned* __restrict__ done,
                                                float* __restrict__ out) {
    __shared__ uint4 hsum4[R4W];  // packed u16-pair column sums (19.7KB)
    __shared__ int wsum[4][NFEAT];
    __shared__ int fin[NFEAT];
    __shared__ unsigned is_last;
    unsigned* hsum = (unsigned*)hsum4;

    // ---- phase 1: packed column sums over RPB_ contiguous rows ----
    const uint4* g4 = (const uint4*)ghist + (size_t)blockIdx.x * RPB_ * R4W;
    uint4 acc0 = {0, 0, 0, 0}, acc1 = {0, 0, 0, 0}, acc2 = {0, 0, 0, 0},
          acc3 = {0, 0, 0, 0}, acc4 = {0, 0, 0, 0};
    const int t = threadIdx.x;
    const bool has4 = (t + 1024) < R4W;  // last slot partial (R4W=1232)
#pragma unroll 2
    for (int r = 0; r < RPB_; ++r) {
        const uint4* row = g4 + r * R4W;
        uint4 v0 = row[t];
        uint4 v1 = row[t + 256];
        uint4 v2 = row[t + 512];
        uint4 v3 = row[t + 768];
        acc0.x += v0.x; acc0.y += v0.y; acc0.z += v0.z; acc0.w += v0.w;
        acc1.x += v1.x; acc1.y += v1.y; acc1.z += v1.z; acc1.w += v1.w;
        acc2.x += v2.x; acc2.y += v2.y; acc2.z += v2.z; acc2.w += v2.w;
        acc3.x += v3.x; acc3.y += v3.y; acc3.z += v3.z; acc3.w += v3.w;
        if (has4) {
            uint4 v4 = row[t + 1024];
            acc4.x += v4.x; acc4.y += v4.y; acc4.z += v4.z; acc4.w += v4.w;
        }
    }
    hsum4[t] = acc0;
    hsum4[t + 256] = acc1;
    hsum4[t + 512] = acc2;
    hsum4[t + 768] = acc3;
    if (has4) hsum4[t + 1024] = acc4;
    __syncthreads();

    // ---- phase 2: dot packed column sums vs compact tables ----
    int acc[NFEAT];
#pragma unroll
    for (int f = 0; f < NFEAT; ++f) acc[f] = 0;

    for (int j = threadIdx.x; j < NBINS; j += 256) {
        const int sh = (j & 1) << 4;
        const int hm = (int)((hsum[j >> 1] >> sh) & 0xFFFFu);
        const int hl = (int)((hsum[WPH + (j >> 1)] >> sh) & 0xFFFFu);
        const int* rm = cm + j * 5;
        const int* rl = cl + j * 5;
#pragma unroll
        for (int k = 0; k < 5; ++k) {
            int wm = rm[k];
            int wl = rl[k];
            acc[4 * k + 0] += hm * ((wm << 24) >> 24) + hl * ((wl << 24) >> 24);
            acc[4 * k + 1] += hm * ((wm << 16) >> 24) + hl * ((wl << 16) >> 24);
            acc[4 * k + 2] += hm * ((wm << 8) >> 24) + hl * ((wl << 8) >> 24);
            acc[4 * k + 3] += hm * (wm >> 24) + hl * (wl >> 24);
        }
    }

    // ---- block reduce -> per-block partial ----
    const int lane = threadIdx.x & 63;
    const int wv = threadIdx.x >> 6;
#pragma unroll
    for (int f = 0; f < NFEAT; ++f) {
        int v = acc[f];
#pragma unroll
        for (int o = 32; o > 0; o >>= 1) v += __shfl_xor(v, o, 64);
        if (lane == 0) wsum[wv][f] = v;
    }
    __syncthreads();
    if (threadIdx.x < NFEAT) {
        int f = threadIdx.x;
        partial[blockIdx.x * NFEAT + f] = wsum[0][f] + wsum[1][f] + wsum[2][f] + wsum[3][f];
    }
    __threadfence();
    __syncthreads();
    if (threadIdx.x == 0) is_last = (atomicAdd(done, 1u) == (unsigned)(FB - 1));
    __syncthreads();

    if (is_last) {
        __threadfence();  // acquire
        if (threadIdx.x < NFEAT) fin[threadIdx.x] = 0;
        __syncthreads();
        for (int i = threadIdx.x; i < FB * NFEAT; i += 256)
            atomicAdd(&fin[i % NFEAT], partial[i]);
        __syncthreads();
        if (threadIdx.x < NFEAT) {
            // mean*4 = S / 2^20 exact in double; RNE rint == jnp.round
            double m4 = (double)fin[threadIdx.x] * (1.0 / 1048576.0);
            float v = (float)(rint(m4) * 0.25);
            v = fminf(fmaxf(v, -32.0f), 31.75f);
            out[threadIdx.x] = v;
        }
    }
}

// ---------------------------------------------------------------------------
// Fallback (R2 verbatim, proven 54us) if ws can't hold the histograms.
// ---------------------------------------------------------------------------
__global__ __launch_bounds__(256) void feat_fallback(const float* __restrict__ xin,
                                                     const float* __restrict__ xs,
                                                     const int* __restrict__ cm,
                                                     const int* __restrict__ cl,
                                                     int* __restrict__ partial,
                                                     unsigned* __restrict__ done,
                                                     float* __restrict__ out) {
    __shared__ int hist[2 * NBINS];
    __shared__ int wsum[4][NFEAT];
    __shared__ unsigned is_last;
    for (int i = threadIdx.x; i < 2 * NBINS; i += 256) hist[i] = 0;
    __syncthreads();

    const float4* a = (const float4*)xin;
    const float4* b = (const float4*)xs;
    for (int g = blockIdx.x * 256 + threadIdx.x; g < G4; g += 1024 * 256) {
        float4 a0 = a[g], a1 = a[g + G4], a2 = a[g + 2 * G4];
        float4 b0 = b[g], b1 = b[g + G4], b2 = b[g + 2 * G4];
        int m0 = (int)fmaf(a0.x, 289.0f, fmaf(a1.x, 17.0f, a2.x));
        int m1 = (int)fmaf(a0.y, 289.0f, fmaf(a1.y, 17.0f, a2.y));
        int m2 = (int)fmaf(a0.z, 289.0f, fmaf(a1.z, 17.0f, a2.z));
        int m3 = (int)fmaf(a0.w, 289.0f, fmaf(a1.w, 17.0f, a2.w));
        int s0 = (int)fmaf(b0.x, 289.0f, fmaf(b1.x, 17.0f, b2.x));
        int s1 = (int)fmaf(b0.y, 289.0f, fmaf(b1.y, 17.0f, b2.y));
        int s2 = (int)fmaf(b0.z, 289.0f, fmaf(b1.z, 17.0f, b2.z));
        int s3 = (int)fmaf(b0.w, 289.0f, fmaf(b1.w, 17.0f, b2.w));
        atomicAdd(&hist[m0], 1);
        atomicAdd(&hist[m1], 1);
        atomicAdd(&hist[m2], 1);
        atomicAdd(&hist[m3], 1);
        atomicAdd(&hist[NBINS + s0], 1);
        atomicAdd(&hist[NBINS + s1], 1);
        atomicAdd(&hist[NBINS + s2], 1);
        atomicAdd(&hist[NBINS + s3], 1);
    }
    __syncthreads();

    int acc[NFEAT];
#pragma unroll
    for (int f = 0; f < NFEAT; ++f) acc[f] = 0;
    for (int j = threadIdx.x; j < NBINS; j += 256) {
        int hm = hist[j];
        int hl = hist[NBINS + j];
        const int* rm = cm + j * 5;
        const int* rl = cl + j * 5;
#pragma unroll
        for (int k = 0; k < 5; ++k) {
            int wm = rm[k];
            int wl = rl[k];
            acc[4 * k + 0] += hm * ((wm << 24) >> 24) + hl * ((wl << 24) >> 24);
            acc[4 * k + 1] += hm * ((wm << 16) >> 24) + hl * ((wl << 16) >> 24);
            acc[4 * k + 2] += hm * ((wm << 8) >> 24) + hl * ((wl << 8) >> 24);
            acc[4 * k + 3] += hm * (wm >> 24) + hl * (wl >> 24);
        }
    }

    const int lane = threadIdx.x & 63;
    const int wv = threadIdx.x >> 6;
#pragma unroll
    for (int f = 0; f < NFEAT; ++f) {
        int v = acc[f];
#pragma unroll
        for (int o = 32; o > 0; o >>= 1) v += __shfl_xor(v, o, 64);
        if (lane == 0) wsum[wv][f] = v;
    }
    __syncthreads();
    if (threadIdx.x < NFEAT) {
        int f = threadIdx.x;
        partial[blockIdx.x * NFEAT + f] = wsum[0][f] + wsum[1][f] + wsum[2][f] + wsum[3][f];
    }
    __threadfence();
    __syncthreads();
    if (threadIdx.x == 0) is_last = (atomicAdd(done, 1u) == 1023u);
    __syncthreads();
    if (is_last) {
        __threadfence();
        if (threadIdx.x < NFEAT) hist[threadIdx.x] = 0;
        __syncthreads();
        for (int i = threadIdx.x; i < 1024 * NFEAT; i += 256)
            atomicAdd(&hist[i % NFEAT], partial[i]);
        __syncthreads();
        if (threadIdx.x < NFEAT) {
            double m4 = (double)hist[threadIdx.x] * (1.0 / 1048576.0);
            float v = (float)(rint(m4) * 0.25);
            v = fminf(fmaxf(v, -32.0f), 31.75f);
            out[threadIdx.x] = v;
        }
    }
}

extern "C" void kernel_launch(void* const* d_in, const int* in_sizes, int n_in,
                              void* d_out, int out_size, void* d_ws, size_t ws_size,
                              hipStream_t stream) {
    const float* xin = (const float*)d_in[0];
    const float* xs = (const float*)d_in[1];
    const int* msb = (const int*)d_in[2];
    const int* lsb = (const int*)d_in[3];
    float* out = (float*)d_out;

    // ws: cm 96KiB | cl 96KiB | partial 80KiB | done (+pad to 16B) | ghist
    char* base = (char*)d_ws;
    int* cm = (int*)base;
    int* cl = (int*)(base + 98304);
    int* partial = (int*)(base + 196608);
    unsigned* done = (unsigned*)(base + 196608 + 81920);
    unsigned* ghist = (unsigned*)(base + 196608 + 82176);  // 16B-aligned
    const size_t hdr = 196608 + 82176;
    const size_t need2048 = hdr + (size_t)2048 * ROWW * 4;  // ~40.7 MB
    const size_t need1024 = hdr + (size_t)1024 * ROWW * 4;  // ~20.5 MB

    compact_k<<<96, 256, 0, stream>>>(msb, lsb, cm, cl, done);
    if (ws_size >= need2048) {
        hist_k<2048><<<2048, 256, 0, stream>>>(xin, xs, ghist);
        colsum_k<8><<<FB, 256, 0, stream>>>(ghist, cm, cl, partial, done, out);
    } else if (ws_size >= need1024) {
        hist_k<1024><<<1024, 256, 0, stream>>>(xin, xs, ghist);
        colsum_k<4><<<FB, 256, 0, stream>>>(ghist, cm, cl, partial, done, out);
    } else {
        feat_fallback<<<1024, 256, 0, stream>>>(xin, xs, cm, cl, partial, done, out);
    }
}